// Round 4
// baseline (314.442 us; speedup 1.0000x reference)
//
#include <hip/hip_runtime.h>
#include <math.h>

// x: (B=64, C=3, H=512, W=512) fp32.  out: (64, 18) fp32.
// Per 8x8 block: |FFT2| at bands (0,1),(1,0),(1,1),(2,2),(3,3),(4,4); mean over
// the 64x64 block grid.
//
// One lane = one whole 8x8 block (8 adjacent columns). One wave = one full
// block-row (8 rows x 512 cols = 16 KB), fully coalesced dwordx4 loads.
//
// DIAGNOSTIC ROUND: kernel is launched TWICE (first into d_ws scratch, then
// into d_out) so the dur_us delta vs the previous round measures one kernel
// dispatch directly (harness reset costs are fixed).

#define IMG_W 512
#define IMG_PIX (512 * 512)

typedef float f4 __attribute__((ext_vector_type(4)));

__global__ __launch_bounds__(256) void dct_band_kernel(const float* __restrict__ x,
                                                       float* __restrict__ out) {
    const int t    = threadIdx.x;
    const int lane = t & 63;
    const int wave = t >> 6;
    const int w    = blockIdx.x * 4 + wave;  // global wave id 0..12287
    const int img  = w >> 6;                 // 0..191 (b*3+c)
    const int bR   = w & 63;                 // block-row 0..63

    const float* p = x + (size_t)img * IMG_PIX
                       + (size_t)(bR * 8) * IMG_W + lane * 8;

    // 16 coalesced dwordx4 loads: rowlo = cols 0..3, rowhi = cols 4..7
    f4 rowlo[8], rowhi[8];
#pragma unroll
    for (int r = 0; r < 8; ++r) {
        rowlo[r] = *(const f4*)(p + (size_t)r * IMG_W);
        rowhi[r] = *(const f4*)(p + (size_t)r * IMG_W + 4);
    }

    const float C1 = 0.70710678118654752440f;
    // e^{-2*pi*i*k/8} = ct[k] - i*st[k]
    const float ct[8] = {1.f,  C1, 0.f, -C1, -1.f, -C1, 0.f,  C1};
    const float st[8] = {0.f,  C1, 1.f,  C1,  0.f, -C1, -1.f, -C1};

    float F01r = 0.f, F01i = 0.f;  // (u=0,v=1)
    float F10r = 0.f, F10i = 0.f;  // (u=1,v=0)
    float F11r = 0.f, F11i = 0.f;  // (u=1,v=1)
    float F22r = 0.f, F22i = 0.f;  // (u=2,v=2)
    float F33r = 0.f, F33i = 0.f;  // (u=3,v=3)
    float F44  = 0.f;              // (u=4,v=4) real

#pragma unroll
    for (int c = 0; c < 8; ++c) {
        const int  ci = c & 3;
        const bool hi = c >= 4;
        const float x0 = hi ? rowhi[0][ci] : rowlo[0][ci];
        const float x1 = hi ? rowhi[1][ci] : rowlo[1][ci];
        const float x2 = hi ? rowhi[2][ci] : rowlo[2][ci];
        const float x3 = hi ? rowhi[3][ci] : rowlo[3][ci];
        const float x4 = hi ? rowhi[4][ci] : rowlo[4][ci];
        const float x5 = hi ? rowhi[5][ci] : rowlo[5][ci];
        const float x6 = hi ? rowhi[6][ci] : rowlo[6][ci];
        const float x7 = hi ? rowhi[7][ci] : rowlo[7][ci];

        // column DFT down the 8 rows: H[u] = sum_r x_r e^{-2*pi*i*u*r/8}
        const float h0  = x0 + x1 + x2 + x3 + x4 + x5 + x6 + x7;
        const float h1r = x0 - x4 + C1 * (x1 - x3 - x5 + x7);
        const float h1i = -(C1 * (x1 + x3 - x5 - x7) + x2 - x6);
        const float h2r = x0 - x2 + x4 - x6;
        const float h2i = -(x1 - x3 + x5 - x7);
        const float h3r = x0 - x4 + C1 * (-x1 + x3 + x5 - x7);
        const float h3i = -(C1 * (x1 + x3 - x5 - x7) - x2 + x6);
        const float h4  = x0 - x1 + x2 - x3 + x4 - x5 + x6 - x7;

        // horizontal twiddles at column c (all compile-time; c unrolled)
        const float c1 = ct[c],           s1 = st[c];            // v=1
        const float c2 = ct[(2 * c) & 7], s2 = st[(2 * c) & 7];  // v=2
        const float c3 = ct[(3 * c) & 7], s3 = st[(3 * c) & 7];  // v=3
        const float w4 = (c & 1) ? -1.f : 1.f;                   // v=4

        // (hr + i*hi)*(ct - i*st) = (hr*ct + hi*st) + i*(hi*ct - hr*st)
        F01r += h0 * c1;               F01i -= h0 * s1;
        F10r += h1r;                   F10i += h1i;
        F11r += h1r * c1 + h1i * s1;   F11i += h1i * c1 - h1r * s1;
        F22r += h2r * c2 + h2i * s2;   F22i += h2i * c2 - h2r * s2;
        F33r += h3r * c3 + h3i * s3;   F33i += h3i * c3 - h3r * s3;
        F44  += h4 * w4;
    }

    float m[6];
    m[0] = sqrtf(F01r * F01r + F01i * F01i);
    m[1] = sqrtf(F10r * F10r + F10i * F10i);
    m[2] = sqrtf(F11r * F11r + F11i * F11i);
    m[3] = sqrtf(F22r * F22r + F22i * F22i);
    m[4] = sqrtf(F33r * F33r + F33i * F33i);
    m[5] = fabsf(F44);

    // wave(64)-level reduce of the 6 magnitudes (one block per lane)
#pragma unroll
    for (int off = 32; off > 0; off >>= 1) {
#pragma unroll
        for (int k = 0; k < 6; ++k) m[k] += __shfl_down(m[k], off);
    }

    __shared__ float red[4][6];
    if (lane == 0) {
#pragma unroll
        for (int k = 0; k < 6; ++k) red[wave][k] = m[k];
    }
    __syncthreads();

    if (t < 6) {
        const float s = red[0][t] + red[1][t] + red[2][t] + red[3][t];
        atomicAdd(&out[img * 6 + t], s * (1.0f / 4096.0f));
    }
}

extern "C" void kernel_launch(void* const* d_in, const int* in_sizes, int n_in,
                              void* d_out, int out_size, void* d_ws, size_t ws_size,
                              hipStream_t stream) {
    const float* x = (const float*)d_in[0];
    float* out = (float*)d_out;
    float* scratch = (float*)d_ws;  // 1152 floats used as a dummy output

    dim3 grid(3072);   // 12288 waves: 192 images x 64 block-rows; 4 waves/WG
    dim3 block(256);

    // --- Launch 1 (timing probe): identical work into scratch. Result unused.
    dct_band_kernel<<<grid, block, 0, stream>>>(x, scratch);

    // --- Launch 2 (real): zero d_out (poisoned 0xAA) then accumulate.
    hipMemsetAsync(d_out, 0, (size_t)out_size * sizeof(float), stream);
    dct_band_kernel<<<grid, block, 0, stream>>>(x, out);
}

// Round 5
// 272.295 us; speedup vs baseline: 1.1548x; 1.1548x over previous
//
#include <hip/hip_runtime.h>
#include <math.h>

// x: (B=64, C=3, H=512, W=512) fp32.  out: (64, 18) fp32.
// Per 8x8 block: |FFT2| at bands (0,1),(1,0),(1,1),(2,2),(3,3),(4,4); mean over
// the 64x64 block grid.
//
// One lane = one whole 8x8 block (8 adjacent columns). One wave = one full
// block-row (8 rows x 512 cols = 16 KB), fully coalesced dwordx4 loads; each
// 64B line touched exactly once. Input is read exactly once (201 MB).
//
// Measured (R4 double-launch diagnostic): one dispatch ~= 38 us vs the 32 us
// HBM read floor (201 MB / 6.3 TB/s) -> ~85% of achievable read BW. The rest
// of dur_us (~232 us) is fixed harness reset cost (ws poison fill ~118 us,
// input restore ~60 us, small fills + graph overhead).

#define IMG_W 512
#define IMG_PIX (512 * 512)

typedef float f4 __attribute__((ext_vector_type(4)));

__global__ __launch_bounds__(256) void dct_band_kernel(const float* __restrict__ x,
                                                       float* __restrict__ out) {
    const int t    = threadIdx.x;
    const int lane = t & 63;
    const int wave = t >> 6;
    const int w    = blockIdx.x * 4 + wave;  // global wave id 0..12287
    const int img  = w >> 6;                 // 0..191 (b*3+c)
    const int bR   = w & 63;                 // block-row 0..63

    const float* p = x + (size_t)img * IMG_PIX
                       + (size_t)(bR * 8) * IMG_W + lane * 8;

    // 16 coalesced dwordx4 loads: rowlo = cols 0..3, rowhi = cols 4..7
    f4 rowlo[8], rowhi[8];
#pragma unroll
    for (int r = 0; r < 8; ++r) {
        rowlo[r] = *(const f4*)(p + (size_t)r * IMG_W);
        rowhi[r] = *(const f4*)(p + (size_t)r * IMG_W + 4);
    }

    const float C1 = 0.70710678118654752440f;
    // e^{-2*pi*i*k/8} = ct[k] - i*st[k]
    const float ct[8] = {1.f,  C1, 0.f, -C1, -1.f, -C1, 0.f,  C1};
    const float st[8] = {0.f,  C1, 1.f,  C1,  0.f, -C1, -1.f, -C1};

    float F01r = 0.f, F01i = 0.f;  // (u=0,v=1)
    float F10r = 0.f, F10i = 0.f;  // (u=1,v=0)
    float F11r = 0.f, F11i = 0.f;  // (u=1,v=1)
    float F22r = 0.f, F22i = 0.f;  // (u=2,v=2)
    float F33r = 0.f, F33i = 0.f;  // (u=3,v=3)
    float F44  = 0.f;              // (u=4,v=4) real

#pragma unroll
    for (int c = 0; c < 8; ++c) {
        const int  ci = c & 3;
        const bool hi = c >= 4;
        const float x0 = hi ? rowhi[0][ci] : rowlo[0][ci];
        const float x1 = hi ? rowhi[1][ci] : rowlo[1][ci];
        const float x2 = hi ? rowhi[2][ci] : rowlo[2][ci];
        const float x3 = hi ? rowhi[3][ci] : rowlo[3][ci];
        const float x4 = hi ? rowhi[4][ci] : rowlo[4][ci];
        const float x5 = hi ? rowhi[5][ci] : rowlo[5][ci];
        const float x6 = hi ? rowhi[6][ci] : rowlo[6][ci];
        const float x7 = hi ? rowhi[7][ci] : rowlo[7][ci];

        // column DFT down the 8 rows: H[u] = sum_r x_r e^{-2*pi*i*u*r/8}
        const float h0  = x0 + x1 + x2 + x3 + x4 + x5 + x6 + x7;
        const float h1r = x0 - x4 + C1 * (x1 - x3 - x5 + x7);
        const float h1i = -(C1 * (x1 + x3 - x5 - x7) + x2 - x6);
        const float h2r = x0 - x2 + x4 - x6;
        const float h2i = -(x1 - x3 + x5 - x7);
        const float h3r = x0 - x4 + C1 * (-x1 + x3 + x5 - x7);
        const float h3i = -(C1 * (x1 + x3 - x5 - x7) - x2 + x6);
        const float h4  = x0 - x1 + x2 - x3 + x4 - x5 + x6 - x7;

        // horizontal twiddles at column c (all compile-time; c unrolled)
        const float c1 = ct[c],           s1 = st[c];            // v=1
        const float c2 = ct[(2 * c) & 7], s2 = st[(2 * c) & 7];  // v=2
        const float c3 = ct[(3 * c) & 7], s3 = st[(3 * c) & 7];  // v=3
        const float w4 = (c & 1) ? -1.f : 1.f;                   // v=4

        // (hr + i*hi)*(ct - i*st) = (hr*ct + hi*st) + i*(hi*ct - hr*st)
        F01r += h0 * c1;               F01i -= h0 * s1;
        F10r += h1r;                   F10i += h1i;
        F11r += h1r * c1 + h1i * s1;   F11i += h1i * c1 - h1r * s1;
        F22r += h2r * c2 + h2i * s2;   F22i += h2i * c2 - h2r * s2;
        F33r += h3r * c3 + h3i * s3;   F33i += h3i * c3 - h3r * s3;
        F44  += h4 * w4;
    }

    float m[6];
    m[0] = sqrtf(F01r * F01r + F01i * F01i);
    m[1] = sqrtf(F10r * F10r + F10i * F10i);
    m[2] = sqrtf(F11r * F11r + F11i * F11i);
    m[3] = sqrtf(F22r * F22r + F22i * F22i);
    m[4] = sqrtf(F33r * F33r + F33i * F33i);
    m[5] = fabsf(F44);

    // wave(64)-level reduce of the 6 magnitudes (one block per lane)
#pragma unroll
    for (int off = 32; off > 0; off >>= 1) {
#pragma unroll
        for (int k = 0; k < 6; ++k) m[k] += __shfl_down(m[k], off);
    }

    __shared__ float red[4][6];
    if (lane == 0) {
#pragma unroll
        for (int k = 0; k < 6; ++k) red[wave][k] = m[k];
    }
    __syncthreads();

    if (t < 6) {
        const float s = red[0][t] + red[1][t] + red[2][t] + red[3][t];
        atomicAdd(&out[img * 6 + t], s * (1.0f / 4096.0f));
    }
}

extern "C" void kernel_launch(void* const* d_in, const int* in_sizes, int n_in,
                              void* d_out, int out_size, void* d_ws, size_t ws_size,
                              hipStream_t stream) {
    const float* x = (const float*)d_in[0];
    float* out = (float*)d_out;

    // d_out is poisoned 0xAA before every call — zero it for the atomics.
    hipMemsetAsync(d_out, 0, (size_t)out_size * sizeof(float), stream);

    // 12288 waves: 192 images x 64 block-rows; 4 waves / WG
    dim3 grid(3072);
    dim3 block(256);
    dct_band_kernel<<<grid, block, 0, stream>>>(x, out);
}